// Round 5
// baseline (327.296 us; speedup 1.0000x reference)
//
#include <hip/hip_runtime.h>
#include <hip/hip_bf16.h>
#include <cstdint>
#include <cstddef>

// Fused multi-head "Head" op on MI355X (gfx950), bf16-MFMA path.
// B=8, S=4096, D=512, T=8, c=512. 64 (b,t) heads, each a 512^3 GEMM chain.
//
// Pipeline (5 dispatches):
//   1. pe_cast:  x_pe = bf16(x + PE)                                [ws]
//   2. cast_w:   Wk,Wq,Wv -> bf16                                   [ws]
//   3. gemm_kq:  k,q = x_pe.W^T + b (fused, A staged once)          [ws]
//   4. gemm_nt:  vT = Wv . x_pe^T + bv (row bias, v transposed)     [ws]
//   5. attn_fused: out = softmax(k.q^T/512) . v   (P in LDS,
//      vt B-frags direct from L2) -> fp32                           [d_out]
// ws requirement: 146,800,640 bytes (~140 MiB).

typedef __bf16 bf16_t;
typedef __bf16 bf16x4 __attribute__((ext_vector_type(4)));
typedef __bf16 bf16x8 __attribute__((ext_vector_type(8)));
typedef float  f32x4  __attribute__((ext_vector_type(4)));

#define GAS __attribute__((address_space(1)))
#define LAS __attribute__((address_space(3)))

// ---------------------------------------------------------------------------
// 1. PE add + cast; one thread owns (s,d4), loops 8 batches (trig amortized).
// ---------------------------------------------------------------------------
__global__ __launch_bounds__(256) void pe_cast_kernel(
    const float* __restrict__ x, bf16_t* __restrict__ xpe)
{
    const float cexp = -0.017988946039015984f; // -ln(10000)/512
    int i = blockIdx.x * 256 + threadIdx.x;    // [0, 4096*128)
    int d4 = i & 127;
    int s  = i >> 7;
    int d  = d4 * 4;
    float fs = (float)s;
    float a0 = fs * __expf(cexp * (float)d);
    float a1 = fs * __expf(cexp * (float)(d + 2));
    float s0, c0, s1, c1;
    sincosf(a0, &s0, &c0);
    sincosf(a1, &s1, &c1);
    size_t base = (size_t)s * 512 + d;
    #pragma unroll
    for (int b = 0; b < 8; ++b) {
        float4 xv = *(const float4*)(x + (size_t)b * 2097152 + base);
        bf16x4 o;
        o[0] = (bf16_t)(xv.x + s0);
        o[1] = (bf16_t)(xv.y + c0);
        o[2] = (bf16_t)(xv.z + s1);
        o[3] = (bf16_t)(xv.w + c1);
        *(bf16x4*)(xpe + (size_t)b * 2097152 + base) = o;
    }
}

// ---------------------------------------------------------------------------
// 2. fp32 -> bf16 cast for the three weight tensors (grid.y selects tensor)
// ---------------------------------------------------------------------------
__global__ __launch_bounds__(256) void cast_w(
    const float* __restrict__ w0, const float* __restrict__ w1, const float* __restrict__ w2,
    bf16_t* __restrict__ o0, bf16_t* __restrict__ o1, bf16_t* __restrict__ o2, int n4)
{
    const float* s = blockIdx.y == 0 ? w0 : (blockIdx.y == 1 ? w1 : w2);
    bf16_t*      o = blockIdx.y == 0 ? o0 : (blockIdx.y == 1 ? o1 : o2);
    for (int i = blockIdx.x * 256 + threadIdx.x; i < n4; i += gridDim.x * 256) {
        float4 v = ((const float4*)s)[i];
        bf16x4 r;
        r[0] = (bf16_t)v.x; r[1] = (bf16_t)v.y; r[2] = (bf16_t)v.z; r[3] = (bf16_t)v.w;
        ((bf16x4*)o)[i] = r;
    }
}

// ---------------------------------------------------------------------------
// 3. Fused k+q projection: k = xpe.Wk^T + bk ; q = xpe.Wq^T + bq.
// 128x128 tile (for both outputs), BK=64, 4 waves 2x2. A (xpe) staged via
// dbuf global_load_lds with rule-#21 XOR swizzle; Wk/Wq B-frags read DIRECT
// from global (weights are tiny & L2-hot: 0.5MB per t, shared by 8 bt/XCD).
// Grid 1024 blocks, XCD-swizzled bijectively.
// ---------------------------------------------------------------------------
__global__ __launch_bounds__(256, 2) void gemm_kq(
    const bf16_t* __restrict__ X, const bf16_t* __restrict__ WK,
    const bf16_t* __restrict__ WQ, bf16_t* __restrict__ Ko,
    bf16_t* __restrict__ Qo, const float* __restrict__ bk,
    const float* __restrict__ bq)
{
    int L  = blockIdx.y * 16 + blockIdx.x;      // 0..1023
    int wk = (L & 7) * 128 + (L >> 3);          // XCD swizzle (bijective)
    int bt = wk >> 4;
    int tile = wk & 15;
    int t  = bt & 7;
    const bf16_t* Ab = X  + (size_t)bt * 262144;
    const bf16_t* Kw = WK + (size_t)t * 262144;
    const bf16_t* Qw = WQ + (size_t)t * 262144;
    int ti = (tile >> 2) << 7;   // A row-tile origin
    int tn = (tile & 3) << 7;    // output col-tile origin

    __shared__ __align__(1024) char lds[32768];  // A dbuf 2x16K

    const int tid  = threadIdx.x;
    const int l    = tid & 63;
    const int w    = tid >> 6;
    const int lrow = l >> 3;
    const int hd   = (l & 7) ^ lrow;       // pre-swizzled global k-chunk
    const int wrow = w >> 1, wcol = w & 1;
    const int rA   = l & 15;
    const int hb   = l >> 4;
    const int x7   = l & 7;

    f32x4 acck[4][4] = {}, accq[4][4] = {};

    auto stage = [&](int buf, int k0) {
        char* ldsA = lds + buf * 16384;
        #pragma unroll
        for (int p = 0; p < 4; ++p) {
            int c    = w * 4 + p;
            int grow = c * 8 + lrow;
            const bf16_t* srcA = Ab + (size_t)(ti + grow) * 512 + k0 + hd * 8;
            __builtin_amdgcn_global_load_lds((GAS void*)srcA, (LAS void*)(ldsA + c * 1024 + l * 16), 16, 0, 0);
        }
    };

    stage(0, 0);
    __syncthreads();
    for (int it = 0; it < 8; ++it) {
        if (it < 7) stage((it + 1) & 1, (it + 1) * 64);
        const char* ldsA = lds + (it & 1) * 16384;
        #pragma unroll
        for (int kk = 0; kk < 2; ++kk) {
            bf16x8 a[4], bK[4], bQ[4];
            #pragma unroll
            for (int m = 0; m < 4; ++m) {
                int off = (wrow * 64 + m * 16 + rA) * 128 + (((kk << 2) | hb) ^ x7) * 16;
                a[m] = *(const bf16x8*)(ldsA + off);
            }
            int kpos = it * 64 + kk * 32 + hb * 8;
            #pragma unroll
            for (int n = 0; n < 4; ++n) {
                int e = tn + wcol * 64 + n * 16 + rA;   // weight row = output col
                bK[n] = *(const bf16x8*)(Kw + (size_t)e * 512 + kpos);
                bQ[n] = *(const bf16x8*)(Qw + (size_t)e * 512 + kpos);
            }
            #pragma unroll
            for (int m = 0; m < 4; ++m)
                #pragma unroll
                for (int n = 0; n < 4; ++n) {
                    acck[m][n] = __builtin_amdgcn_mfma_f32_16x16x32_bf16(a[m], bK[n], acck[m][n], 0, 0, 0);
                    accq[m][n] = __builtin_amdgcn_mfma_f32_16x16x32_bf16(a[m], bQ[n], accq[m][n], 0, 0, 0);
                }
        }
        __syncthreads();
    }

    const float* bkT = bk + t * 512;
    const float* bqT = bq + t * 512;
    int r0 = ti + wrow * 64;
    int c0 = tn + wcol * 64;
    #pragma unroll
    for (int m = 0; m < 4; ++m)
        #pragma unroll
        for (int n = 0; n < 4; ++n) {
            int col = c0 + n * 16 + rA;
            float bkc = bkT[col], bqc = bqT[col];
            #pragma unroll
            for (int r = 0; r < 4; ++r) {
                int row = r0 + m * 16 + hb * 4 + r;
                size_t off = (size_t)bt * 262144 + (size_t)row * 512 + col;
                Ko[off] = (bf16_t)(acck[m][n][r] + bkc);
                Qo[off] = (bf16_t)(accq[m][n][r] + bqc);
            }
        }
}

// ---------------------------------------------------------------------------
// 4. NT GEMM (used for vT = Wv . xpe^T + bv, row bias). Proven R4 structure:
// 128x128 tile, BK=64, dbuf global_load_lds staging, both-sides XOR swizzle.
// ---------------------------------------------------------------------------
template<int BIAS_MODE, int OUT_BF16>   // BIAS: 0 none, 1 col, 2 row
__global__ __launch_bounds__(256, 2) void gemm_nt(
    const bf16_t* __restrict__ A, const bf16_t* __restrict__ Bm,
    void* __restrict__ C, const float* __restrict__ bias,
    long aStr, long bStr, long cStr, int aByT, int bByT, float scale)
{
    constexpr int LD = 512;
    int L  = blockIdx.y * 16 + blockIdx.x;
    int wk = (L & 7) * 128 + (L >> 3);
    int bt = wk >> 4;
    int tile = wk & 15;
    int t  = bt & 7;
    const bf16_t* Ab = A  + (size_t)(aByT ? t : bt) * aStr;
    const bf16_t* Bb = Bm + (size_t)(bByT ? t : bt) * bStr;
    int ti = (tile >> 2) << 7;
    int tn = (tile & 3) << 7;

    __shared__ __align__(1024) char lds[65536];

    const int tid  = threadIdx.x;
    const int l    = tid & 63;
    const int w    = tid >> 6;
    const int lrow = l >> 3;
    const int hd   = (l & 7) ^ lrow;
    const int wrow = w >> 1, wcol = w & 1;
    const int rA   = l & 15;
    const int hb   = l >> 4;
    const int x7   = l & 7;

    f32x4 acc[4][4] = {};

    auto stage = [&](int buf, int k0) {
        char* ldsA = lds + buf * 32768;
        char* ldsB = ldsA + 16384;
        #pragma unroll
        for (int p = 0; p < 4; ++p) {
            int c    = w * 4 + p;
            int grow = c * 8 + lrow;
            const bf16_t* srcA = Ab + (size_t)(ti + grow) * LD + k0 + hd * 8;
            const bf16_t* srcB = Bb + (size_t)(tn + grow) * LD + k0 + hd * 8;
            __builtin_amdgcn_global_load_lds((GAS void*)srcA, (LAS void*)(ldsA + c * 1024 + l * 16), 16, 0, 0);
            __builtin_amdgcn_global_load_lds((GAS void*)srcB, (LAS void*)(ldsB + c * 1024 + l * 16), 16, 0, 0);
        }
    };

    stage(0, 0);
    __syncthreads();
    for (int it = 0; it < 8; ++it) {
        if (it < 7) stage((it + 1) & 1, (it + 1) * 64);
        const char* ldsA = lds + (it & 1) * 32768;
        const char* ldsB = ldsA + 16384;
        #pragma unroll
        for (int kk = 0; kk < 2; ++kk) {
            bf16x8 a[4], b[4];
            #pragma unroll
            for (int m = 0; m < 4; ++m) {
                int off = (wrow * 64 + m * 16 + rA) * 128 + (((kk << 2) | hb) ^ x7) * 16;
                a[m] = *(const bf16x8*)(ldsA + off);
            }
            #pragma unroll
            for (int n = 0; n < 4; ++n) {
                int off = (wcol * 64 + n * 16 + rA) * 128 + (((kk << 2) | hb) ^ x7) * 16;
                b[n] = *(const bf16x8*)(ldsB + off);
            }
            #pragma unroll
            for (int m = 0; m < 4; ++m)
                #pragma unroll
                for (int n = 0; n < 4; ++n)
                    acc[m][n] = __builtin_amdgcn_mfma_f32_16x16x32_bf16(a[m], b[n], acc[m][n], 0, 0, 0);
        }
        __syncthreads();
    }

    const float* biasT = bias ? bias + t * 512 : bias;
    int r0 = ti + wrow * 64;
    int c0 = tn + wcol * 64;
    #pragma unroll
    for (int m = 0; m < 4; ++m)
        #pragma unroll
        for (int n = 0; n < 4; ++n) {
            int col = c0 + n * 16 + rA;
            float bc = (BIAS_MODE == 1) ? biasT[col] : 0.0f;
            f32x4 v = acc[m][n];
            #pragma unroll
            for (int r = 0; r < 4; ++r) {
                int row = r0 + m * 16 + hb * 4 + r;
                float val = v[r] * scale + ((BIAS_MODE == 2) ? biasT[row] : bc);
                size_t off = (size_t)bt * cStr + (size_t)row * LD + col;
                if (OUT_BF16) ((bf16_t*)C)[off] = (bf16_t)val;
                else          ((float*)C)[off]  = val;
            }
        }
}

// ---------------------------------------------------------------------------
// 5. Fully fused attention: out[i][e] = softmax_row(k.q^T/512)[i][:] . v[:][e]
// Block = 128 score-rows (i) x full 512 cols (j); 8 waves.
// Phase A (QK^T): R4's proven scores_softmax structure (dbuf staging, 64B-row
//   tiles, (row&3) XOR swizzle), acc = full 128x512 scores in registers.
// Softmax: shfl 16-group reduce + LDS [128][4] cross-wave combine.
// P-write: bf16 to LDS [128 rows][1KB], slot' = (j>>3) ^ (i&7) XOR swizzle
//   (aliases the dead staging region).
// Phase B (PV): A-frags from P-LDS (~2-way conflicts), B-frags (vt) DIRECT
//   from global/L2 (vt = 0.5MB/bt, shared by 4 blocks), acc2 128x512 fp32.
// LDS 132K -> 1 block/CU; grid 256 = one block per CU, XCD-swizzled.
// ---------------------------------------------------------------------------
__global__ __launch_bounds__(512, 2) void attn_fused(
    const bf16_t* __restrict__ K, const bf16_t* __restrict__ Q,
    const bf16_t* __restrict__ VT, float* __restrict__ Out)
{
    int L  = blockIdx.x;                 // 0..255
    int wkd = (L & 7) * 32 + (L >> 3);   // bijective XCD swizzle
    int bt = wkd >> 2;
    int ti = (wkd & 3) << 7;             // score-row tile origin
    const bf16_t* Kb = K  + (size_t)bt * 262144;
    const bf16_t* Qb = Q  + (size_t)bt * 262144;
    const bf16_t* Vb = VT + (size_t)bt * 262144;

    __shared__ __align__(1024) char smem[135168];
    // phase A: [0,16384) kA dbuf; [16384,81920) qB dbuf
    // phase B: [0,131072) P (128 rows x 1KB, XOR-swizzled) -- aliases staging
    // always:  [131072,133120) smax [128][4]; [133120,135168) ssum [128][4]
    float* smax_p = (float*)(smem + 131072);
    float* ssum_p = (float*)(smem + 133120);

    const int tid  = threadIdx.x;
    const int l    = tid & 63;
    const int wv   = tid >> 6;           // 0..7
    const int wrow = wv >> 2;            // 0..1 (64 score-rows each)
    const int wcol = wv & 3;             // 0..3 (128 cols each)
    const int rA   = l & 15;
    const int hb   = l >> 4;             // 0..3

    f32x4 acc[4][8] = {};                // scores: [m over i][n over j]

    auto stage = [&](int buf, int d0) {
        char* kA = smem + buf * 8192;
        char* qB = smem + 16384 + buf * 32768;
        {
            int row = tid >> 2, slot = tid & 3;
            const bf16_t* src = Kb + (size_t)(ti + row) * 512 + d0 + (slot ^ (row & 3)) * 8;
            __builtin_amdgcn_global_load_lds((GAS void*)src, (LAS void*)(kA + tid * 16), 16, 0, 0);
        }
        #pragma unroll
        for (int u = 0; u < 4; ++u) {
            int q2 = u * 512 + tid;
            int row = q2 >> 2, slot = q2 & 3;
            const bf16_t* src = Qb + (size_t)row * 512 + d0 + (slot ^ (row & 3)) * 8;
            __builtin_amdgcn_global_load_lds((GAS void*)src, (LAS void*)(qB + q2 * 16), 16, 0, 0);
        }
    };

    stage(0, 0);
    __syncthreads();
    for (int it = 0; it < 16; ++it) {
        if (it < 15) stage((it + 1) & 1, (it + 1) * 32);
        const char* kA = smem + (it & 1) * 8192;
        const char* qB = smem + 16384 + (it & 1) * 32768;
        bf16x8 a[4], b[8];
        #pragma unroll
        for (int m = 0; m < 4; ++m) {
            int row = wrow * 64 + m * 16 + rA;
            a[m] = *(const bf16x8*)(kA + row * 64 + (hb ^ (row & 3)) * 16);
        }
        #pragma unroll
        for (int n = 0; n < 8; ++n) {
            int row = wcol * 128 + n * 16 + rA;
            b[n] = *(const bf16x8*)(qB + row * 64 + (hb ^ (row & 3)) * 16);
        }
        #pragma unroll
        for (int m = 0; m < 4; ++m)
            #pragma unroll
            for (int n = 0; n < 8; ++n)
                acc[m][n] = __builtin_amdgcn_mfma_f32_16x16x32_bf16(a[m], b[n], acc[m][n], 0, 0, 0);
        __syncthreads();
    }

    // ---- softmax over full 512-col rows (scale 1/512 inside exp) ----
    float red[4][4];
    #pragma unroll
    for (int m = 0; m < 4; ++m)
        #pragma unroll
        for (int r = 0; r < 4; ++r) {
            float mx = acc[m][0][r];
            #pragma unroll
            for (int n = 1; n < 8; ++n) mx = fmaxf(mx, acc[m][n][r]);
            #pragma unroll
            for (int o = 1; o < 16; o <<= 1) mx = fmaxf(mx, __shfl_xor(mx, o, 64));
            red[m][r] = mx;
        }
    if (rA < 4) {
        #pragma unroll
        for (int m = 0; m < 4; ++m)
            smax_p[(wrow * 64 + m * 16 + hb * 4 + rA) * 4 + wcol] = red[m][rA];
    }
    __syncthreads();
    float rstat[4][4];
    #pragma unroll
    for (int m = 0; m < 4; ++m)
        #pragma unroll
        for (int r = 0; r < 4; ++r) {
            f32x4 p4 = *(const f32x4*)(smax_p + (wrow * 64 + m * 16 + hb * 4 + r) * 4);
            rstat[m][r] = fmaxf(fmaxf(p4[0], p4[1]), fmaxf(p4[2], p4[3]));
        }
    const float inv512 = 1.0f / 512.0f;
    #pragma unroll
    for (int m = 0; m < 4; ++m)
        #pragma unroll
        for (int r = 0; r < 4; ++r) {
            float sum = 0.0f;
            #pragma unroll
            for (int n = 0; n < 8; ++n) {
                float e = __expf((acc[m][n][r] - rstat[m][r]) * inv512);
                acc[m][n][r] = e;
                sum += e;
            }
            #pragma unroll
            for (int o = 1; o < 16; o <<= 1) sum += __shfl_xor(sum, o, 64);
            red[m][r] = sum;
        }
    if (rA < 4) {
        #pragma unroll
        for (int m = 0; m < 4; ++m)
            ssum_p[(wrow * 64 + m * 16 + hb * 4 + rA) * 4 + wcol] = red[m][rA];
    }
    __syncthreads();
    #pragma unroll
    for (int m = 0; m < 4; ++m)
        #pragma unroll
        for (int r = 0; r < 4; ++r) {
            f32x4 p4 = *(const f32x4*)(ssum_p + (wrow * 64 + m * 16 + hb * 4 + r) * 4);
            rstat[m][r] = 1.0f / ((p4[0] + p4[1]) + (p4[2] + p4[3]));
        }

    // ---- write P = attn (bf16) into LDS, XOR-swizzled ----
    // i row, col j: byte = i*1024 + ((j>>3)^(i&7))*16 + (j&7)*2
    #pragma unroll
    for (int m = 0; m < 4; ++m)
        #pragma unroll
        for (int n = 0; n < 8; ++n) {
            int j = wcol * 128 + n * 16 + rA;
            int jslot = j >> 3, jrem = (j & 7) * 2;
            #pragma unroll
            for (int r = 0; r < 4; ++r) {
                int i = wrow * 64 + m * 16 + hb * 4 + r;
                *(bf16_t*)(smem + i * 1024 + ((jslot ^ (i & 7)) << 4) + jrem) =
                    (bf16_t)(acc[m][n][r] * rstat[m][r]);
            }
        }
    __syncthreads();

    // ---- PV: out[i][e] = sum_j P[i][j] * vt[e][j]  (NT, B direct from L2) ----
    f32x4 acc2[4][8] = {};               // [m over i(64)][n over e(128)]
    for (int it = 0; it < 16; ++it) {
        int j0 = it * 32;
        bf16x8 a[4], b[8];
        #pragma unroll
        for (int m = 0; m < 4; ++m) {
            int i = wrow * 64 + m * 16 + rA;
            a[m] = *(const bf16x8*)(smem + i * 1024 + ((((it << 2) | hb) ^ (i & 7)) << 4));
        }
        #pragma unroll
        for (int n = 0; n < 8; ++n) {
            int e = wcol * 128 + n * 16 + rA;
            b[n] = *(const bf16x8*)(Vb + (size_t)e * 512 + j0 + hb * 8);
        }
        #pragma unroll
        for (int m = 0; m < 4; ++m)
            #pragma unroll
            for (int n = 0; n < 8; ++n)
                acc2[m][n] = __builtin_amdgcn_mfma_f32_16x16x32_bf16(a[m], b[n], acc2[m][n], 0, 0, 0);
    }

    // epilogue: D frag col = e, row = i
    #pragma unroll
    for (int m = 0; m < 4; ++m)
        #pragma unroll
        for (int n = 0; n < 8; ++n) {
            int e = wcol * 128 + n * 16 + rA;
            #pragma unroll
            for (int r = 0; r < 4; ++r) {
                int i = ti + wrow * 64 + m * 16 + hb * 4 + r;
                Out[(size_t)bt * 262144 + (size_t)i * 512 + e] = acc2[m][n][r];
            }
        }
}

// ---------------------------------------------------------------------------
extern "C" void kernel_launch(void* const* d_in, const int* in_sizes, int n_in,
                              void* d_out, int out_size, void* d_ws, size_t ws_size,
                              hipStream_t stream)
{
    const float* x  = (const float*)d_in[0];
    const float* Wk = (const float*)d_in[1];
    const float* bk = (const float*)d_in[2];
    const float* Wq = (const float*)d_in[3];
    const float* bq = (const float*)d_in[4];
    const float* Wv = (const float*)d_in[5];
    const float* bv = (const float*)d_in[6];
    float* out = (float*)d_out;
    char*  ws  = (char*)d_ws;

    bf16_t* k    = (bf16_t*)(ws + 0);          // 33.55 MB
    bf16_t* q    = (bf16_t*)(ws + 33554432);   // 33.55 MB
    bf16_t* vt   = (bf16_t*)(ws + 67108864);   // 33.55 MB  v^T: [bt][e][j]
    bf16_t* xpe  = (bf16_t*)(ws + 100663296);  // 33.55 MB
    bf16_t* wkb  = (bf16_t*)(ws + 134217728);
    bf16_t* wqb  = (bf16_t*)(ws + 138412032);
    bf16_t* wvb  = (bf16_t*)(ws + 142606336);

    const long S2 = 262144;  // 512*512 per-(b,t)/per-t stride

    pe_cast_kernel<<<2048, 256, 0, stream>>>(x, xpe);
    cast_w<<<dim3(512, 3), 256, 0, stream>>>(Wk, Wq, Wv, wkb, wqb, wvb, (8 * 512 * 512) / 4);

    dim3 gg(16, 64);
    // k,q fused projection
    gemm_kq<<<gg, 256, 0, stream>>>(xpe, wkb, wqb, k, q, bk, bq);
    // vT = Wv . xpe^T + bv
    gemm_nt<2, 1><<<gg, 256, 0, stream>>>(wvb, xpe, vt, bv, S2, S2, S2, 1, 0, 1.0f);
    // out = softmax(k.q^T/512) . v   (fully fused)
    attn_fused<<<256, 512, 0, stream>>>(k, q, vt, out);
}

// Round 6
// 284.713 us; speedup vs baseline: 1.1496x; 1.1496x over previous
//
#include <hip/hip_runtime.h>
#include <hip/hip_bf16.h>
#include <cstdint>
#include <cstddef>

// Fused multi-head "Head" op on MI355X (gfx950), bf16-MFMA path.
// B=8, S=4096, D=512, T=8, c=512. 64 (b,t) heads, each a 512^3 GEMM chain.
//
// Pipeline (5 dispatches):
//   1. prep:    x_pe = bf16(x + PE)  +  Wk,Wq,Wv -> bf16            [ws]
//   2. gemm_nt: k  = x_pe.Wk^T + bk   (col bias)                    [ws]
//   3. gemm_nt: q  = x_pe.Wq^T + bq                                 [ws]
//   4. gemm_nt: vT = Wv.x_pe^T + bv   (row bias; v transposed)      [ws]
//   5. attn_fused: out = softmax(k.q^T/512).v  -- P in LDS, vt
//      staged via coalesced global_load_lds slices -> fp32          [d_out]
// All grids head-clustered per XCD (xcd = t) for L2 weight/head reuse.
// ws requirement: 146,800,640 bytes (~140 MiB).

typedef __bf16 bf16_t;
typedef __bf16 bf16x4 __attribute__((ext_vector_type(4)));
typedef __bf16 bf16x8 __attribute__((ext_vector_type(8)));
typedef float  f32x4  __attribute__((ext_vector_type(4)));

#define GAS __attribute__((address_space(1)))
#define LAS __attribute__((address_space(3)))

// ---------------------------------------------------------------------------
// 1. prep: blocks [0,2048) do PE-add+cast (trig amortized over batch);
//          blocks [2048,3072) cast the three weight tensors.
// ---------------------------------------------------------------------------
__global__ __launch_bounds__(256) void prep_kernel(
    const float* __restrict__ x, bf16_t* __restrict__ xpe,
    const float* __restrict__ w0, const float* __restrict__ w1,
    const float* __restrict__ w2, bf16_t* __restrict__ o0,
    bf16_t* __restrict__ o1, bf16_t* __restrict__ o2)
{
    if (blockIdx.x < 2048) {
        const float cexp = -0.017988946039015984f; // -ln(10000)/512
        int i = blockIdx.x * 256 + threadIdx.x;    // [0, 4096*128)
        int d4 = i & 127;
        int s  = i >> 7;
        int d  = d4 * 4;
        float fs = (float)s;
        float a0 = fs * __expf(cexp * (float)d);
        float a1 = fs * __expf(cexp * (float)(d + 2));
        float s0, c0, s1, c1;
        sincosf(a0, &s0, &c0);
        sincosf(a1, &s1, &c1);
        size_t base = (size_t)s * 512 + d;
        #pragma unroll
        for (int b = 0; b < 8; ++b) {
            float4 xv = *(const float4*)(x + (size_t)b * 2097152 + base);
            bf16x4 o;
            o[0] = (bf16_t)(xv.x + s0);
            o[1] = (bf16_t)(xv.y + c0);
            o[2] = (bf16_t)(xv.z + s1);
            o[3] = (bf16_t)(xv.w + c1);
            *(bf16x4*)(xpe + (size_t)b * 2097152 + base) = o;
        }
    } else {
        // 3 x 2,097,152 elems = 1,572,864 float4; 1024 blocks grid-stride
        const int per = 524288;  // float4 per tensor
        for (int i = (blockIdx.x - 2048) * 256 + threadIdx.x; i < 3 * per;
             i += 1024 * 256) {
            int f = i / per, off = i - f * per;
            const float* s = f == 0 ? w0 : (f == 1 ? w1 : w2);
            bf16_t*      o = f == 0 ? o0 : (f == 1 ? o1 : o2);
            float4 v = ((const float4*)s)[off];
            bf16x4 r;
            r[0] = (bf16_t)v.x; r[1] = (bf16_t)v.y;
            r[2] = (bf16_t)v.z; r[3] = (bf16_t)v.w;
            ((bf16x4*)o)[off] = r;
        }
    }
}

// ---------------------------------------------------------------------------
// NT GEMM: C[m][n] = scale*sum_k A[m][k]*B[n][k] (+bias). M=N=K=512.
// 128x128 tile, BK=64, 4 waves 2x2, dbuf global_load_lds staging, rule-#21
// both-sides XOR swizzle. Head-clustered grid: xcd = L&7 = t, so all blocks
// sharing weight[t] sit on one XCD's L2.
// ---------------------------------------------------------------------------
template<int BIAS_MODE, int OUT_BF16>   // BIAS: 0 none, 1 col, 2 row
__global__ __launch_bounds__(256, 2) void gemm_nt(
    const bf16_t* __restrict__ A, const bf16_t* __restrict__ Bm,
    void* __restrict__ C, const float* __restrict__ bias,
    long aStr, long bStr, long cStr, int aByT, int bByT, float scale)
{
    constexpr int LD = 512;
    int L  = blockIdx.y * 16 + blockIdx.x;      // 0..1023
    int t  = L & 7;                             // XCD id = head id
    int b  = (L >> 3) & 7;
    int tile = L >> 6;                          // 0..15
    int bt = (b << 3) | t;
    const bf16_t* Ab = A  + (size_t)(aByT ? t : bt) * aStr;
    const bf16_t* Bb = Bm + (size_t)(bByT ? t : bt) * bStr;
    int ti = (tile >> 2) << 7;
    int tn = (tile & 3) << 7;

    __shared__ __align__(1024) char lds[65536];

    const int tid  = threadIdx.x;
    const int l    = tid & 63;
    const int w    = tid >> 6;
    const int lrow = l >> 3;
    const int hd   = (l & 7) ^ lrow;       // pre-swizzled global k-chunk
    const int wrow = w >> 1, wcol = w & 1;
    const int rA   = l & 15;
    const int hb   = l >> 4;
    const int x7   = l & 7;

    f32x4 acc[4][4] = {};

    auto stage = [&](int buf, int k0) {
        char* ldsA = lds + buf * 32768;
        char* ldsB = ldsA + 16384;
        #pragma unroll
        for (int p = 0; p < 4; ++p) {
            int c    = w * 4 + p;
            int grow = c * 8 + lrow;
            const bf16_t* srcA = Ab + (size_t)(ti + grow) * LD + k0 + hd * 8;
            const bf16_t* srcB = Bb + (size_t)(tn + grow) * LD + k0 + hd * 8;
            __builtin_amdgcn_global_load_lds((GAS void*)srcA, (LAS void*)(ldsA + c * 1024 + l * 16), 16, 0, 0);
            __builtin_amdgcn_global_load_lds((GAS void*)srcB, (LAS void*)(ldsB + c * 1024 + l * 16), 16, 0, 0);
        }
    };

    stage(0, 0);
    __syncthreads();
    for (int it = 0; it < 8; ++it) {
        if (it < 7) stage((it + 1) & 1, (it + 1) * 64);
        const char* ldsA = lds + (it & 1) * 32768;
        const char* ldsB = ldsA + 16384;
        #pragma unroll
        for (int kk = 0; kk < 2; ++kk) {
            bf16x8 a[4], bb[4];
            #pragma unroll
            for (int m = 0; m < 4; ++m) {
                int off = (wrow * 64 + m * 16 + rA) * 128 + (((kk << 2) | hb) ^ x7) * 16;
                a[m] = *(const bf16x8*)(ldsA + off);
            }
            #pragma unroll
            for (int n = 0; n < 4; ++n) {
                int off = (wcol * 64 + n * 16 + rA) * 128 + (((kk << 2) | hb) ^ x7) * 16;
                bb[n] = *(const bf16x8*)(ldsB + off);
            }
            #pragma unroll
            for (int m = 0; m < 4; ++m)
                #pragma unroll
                for (int n = 0; n < 4; ++n)
                    acc[m][n] = __builtin_amdgcn_mfma_f32_16x16x32_bf16(a[m], bb[n], acc[m][n], 0, 0, 0);
        }
        __syncthreads();
    }

    const float* biasT = bias ? bias + t * 512 : bias;
    int r0 = ti + wrow * 64;
    int c0 = tn + wcol * 64;
    #pragma unroll
    for (int m = 0; m < 4; ++m)
        #pragma unroll
        for (int n = 0; n < 4; ++n) {
            int col = c0 + n * 16 + rA;
            float bc = (BIAS_MODE == 1) ? biasT[col] : 0.0f;
            f32x4 v = acc[m][n];
            #pragma unroll
            for (int r = 0; r < 4; ++r) {
                int row = r0 + m * 16 + hb * 4 + r;
                float val = v[r] * scale + ((BIAS_MODE == 2) ? biasT[row] : bc);
                size_t off = (size_t)bt * cStr + (size_t)row * LD + col;
                if (OUT_BF16) ((bf16_t*)C)[off] = (bf16_t)val;
                else          ((float*)C)[off]  = val;
            }
        }
}

// ---------------------------------------------------------------------------
// 5. Fully fused attention. Block = 64 score-rows x full 512 cols; 8 waves,
// wave wv owns j-range (phase A) / e-range (phase B) [wv*64, wv*64+64).
// LDS map: [0,8K) kA dbuf (2x4K); [8K,72K) qB/vt dbuf (2x32K);
//          [72K,136K) P 64 rows x 1KB (XOR-swizzled); [136K,140K) reduce.
// Phase A: scores acc[4][4] in regs, dbuf-staged k,q slices (BK=32).
// Softmax: shfl 16-group + LDS [64][8] cross-wave combine; P -> LDS bf16.
// Phase B: PV with A from P-LDS, B = vt staged in coalesced 32K j-slices.
// Grid 512: xcd = L&7, bt = (L>>6)*8 + xcd (all 8 i-tiles of a head on one
// XCD -> q/vt served from that XCD's L2). 140KB LDS -> 1 block/CU.
// ---------------------------------------------------------------------------
__global__ __launch_bounds__(512) void attn_fused(
    const bf16_t* __restrict__ K, const bf16_t* __restrict__ Q,
    const bf16_t* __restrict__ VT, float* __restrict__ Out)
{
    int L  = blockIdx.x;                       // 0..511
    int bt = ((L >> 6) << 3) | (L & 7);        // head-clustered per XCD
    int ti = ((L >> 3) & 7) << 6;              // i-tile origin (64 rows)
    const bf16_t* Kb = K  + (size_t)bt * 262144;
    const bf16_t* Qb = Q  + (size_t)bt * 262144;
    const bf16_t* Vb = VT + (size_t)bt * 262144;

    __shared__ __align__(1024) char smem[143360];
    char* Pl = smem + 73728;                   // P: 64 x 1KB
    float* smax_p = (float*)(smem + 139264);   // [64][8]
    float* ssum_p = (float*)(smem + 141312);   // [64][8]

    const int tid = threadIdx.x;
    const int l   = tid & 63;
    const int wv  = tid >> 6;            // 0..7
    const int rA  = l & 15;
    const int hb  = l >> 4;              // 0..3
    const int key = (rA >> 1) & 3;       // 2-way-free read swizzle key

    // staging decode (shared by k/q/vt stagers)
    const int srow = tid >> 2;           // 0..127
    const int sslot = tid & 3;

    f32x4 acc[4][4] = {};                // scores: [m over i][n over j(wave)]

    auto stageKQ = [&](int buf, int d0) {
        char* kA = smem + buf * 4096;
        char* qB = smem + 8192 + buf * 32768;
        if (tid < 256) {                 // kA: 64 rows x 64B
            const bf16_t* src = Kb + (size_t)(ti + srow) * 512 + d0 +
                                (sslot ^ ((srow >> 1) & 3)) * 8;
            __builtin_amdgcn_global_load_lds((GAS void*)src, (LAS void*)(kA + tid * 16), 16, 0, 0);
        }
        #pragma unroll
        for (int u = 0; u < 4; ++u) {    // qB: 512 rows x 64B
            int q2 = u * 512 + tid;
            int row = q2 >> 2, slot = q2 & 3;
            const bf16_t* src = Qb + (size_t)row * 512 + d0 +
                                (slot ^ ((row >> 1) & 3)) * 8;
            __builtin_amdgcn_global_load_lds((GAS void*)src, (LAS void*)(qB + q2 * 16), 16, 0, 0);
        }
    };

    stageKQ(0, 0);
    __syncthreads();
    for (int it = 0; it < 16; ++it) {
        if (it < 15) stageKQ((it + 1) & 1, (it + 1) * 32);
        const char* kA = smem + (it & 1) * 4096;
        const char* qB = smem + 8192 + (it & 1) * 32768;
        bf16x8 a[4], b[4];
        #pragma unroll
        for (int m = 0; m < 4; ++m)
            a[m] = *(const bf16x8*)(kA + (m * 16 + rA) * 64 + ((hb ^ key) << 4));
        #pragma unroll
        for (int n = 0; n < 4; ++n) {
            int j = wv * 64 + n * 16 + rA;
            b[n] = *(const bf16x8*)(qB + j * 64 + ((hb ^ key) << 4));
        }
        #pragma unroll
        for (int m = 0; m < 4; ++m)
            #pragma unroll
            for (int n = 0; n < 4; ++n)
                acc[m][n] = __builtin_amdgcn_mfma_f32_16x16x32_bf16(a[m], b[n], acc[m][n], 0, 0, 0);
        __syncthreads();
    }

    // ---- softmax over full 512-col rows; scale 1/512 inside exp ----
    float red[4][4];
    #pragma unroll
    for (int m = 0; m < 4; ++m)
        #pragma unroll
        for (int r = 0; r < 4; ++r) {
            float mx = acc[m][0][r];
            #pragma unroll
            for (int n = 1; n < 4; ++n) mx = fmaxf(mx, acc[m][n][r]);
            #pragma unroll
            for (int o = 1; o < 16; o <<= 1) mx = fmaxf(mx, __shfl_xor(mx, o, 64));
            red[m][r] = mx;
        }
    if (rA < 4) {
        #pragma unroll
        for (int m = 0; m < 4; ++m)
            smax_p[(m * 16 + hb * 4 + rA) * 8 + wv] = red[m][rA];
    }
    __syncthreads();
    float rstat[4][4];
    #pragma unroll
    for (int m = 0; m < 4; ++m)
        #pragma unroll
        for (int r = 0; r < 4; ++r) {
            int row = m * 16 + hb * 4 + r;
            f32x4 p0 = *(const f32x4*)(smax_p + row * 8);
            f32x4 p1 = *(const f32x4*)(smax_p + row * 8 + 4);
            rstat[m][r] = fmaxf(fmaxf(fmaxf(p0[0], p0[1]), fmaxf(p0[2], p0[3])),
                                fmaxf(fmaxf(p1[0], p1[1]), fmaxf(p1[2], p1[3])));
        }
    const float inv512 = 1.0f / 512.0f;
    #pragma unroll
    for (int m = 0; m < 4; ++m)
        #pragma unroll
        for (int r = 0; r < 4; ++r) {
            float sum = 0.0f;
            #pragma unroll
            for (int n = 0; n < 4; ++n) {
                float e = __expf((acc[m][n][r] - rstat[m][r]) * inv512);
                acc[m][n][r] = e;
                sum += e;
            }
            #pragma unroll
            for (int o = 1; o < 16; o <<= 1) sum += __shfl_xor(sum, o, 64);
            red[m][r] = sum;
        }
    if (rA < 4) {
        #pragma unroll
        for (int m = 0; m < 4; ++m)
            ssum_p[(m * 16 + hb * 4 + rA) * 8 + wv] = red[m][rA];
    }
    __syncthreads();
    #pragma unroll
    for (int m = 0; m < 4; ++m)
        #pragma unroll
        for (int r = 0; r < 4; ++r) {
            int row = m * 16 + hb * 4 + r;
            f32x4 p0 = *(const f32x4*)(ssum_p + row * 8);
            f32x4 p1 = *(const f32x4*)(ssum_p + row * 8 + 4);
            rstat[m][r] = 1.0f / (((p0[0] + p0[1]) + (p0[2] + p0[3])) +
                                  ((p1[0] + p1[1]) + (p1[2] + p1[3])));
        }

    // ---- P -> LDS bf16, swizzled: byte = i*1024 + ((j>>3 ^ (i&7))<<4) + (j&7)*2
    #pragma unroll
    for (int m = 0; m < 4; ++m)
        #pragma unroll
        for (int n = 0; n < 4; ++n) {
            int j = wv * 64 + n * 16 + rA;
            int jslot = j >> 3, jrem = (j & 7) * 2;
            #pragma unroll
            for (int r = 0; r < 4; ++r) {
                int i = m * 16 + hb * 4 + r;
                *(bf16_t*)(Pl + i * 1024 + ((jslot ^ (i & 7)) << 4) + jrem) =
                    (bf16_t)(acc[m][n][r] * rstat[m][r]);
            }
        }
    __syncthreads();

    // ---- PV: out[i][e] = sum_j P[i][j] * vt[e][j]; vt staged in j-slices ----
    auto stageV = [&](int buf, int j0) {
        char* vB = smem + 8192 + buf * 32768;
        #pragma unroll
        for (int u = 0; u < 4; ++u) {    // vt slice: 512 e-rows x 64B
            int q2 = u * 512 + tid;
            int e = q2 >> 2, slot = q2 & 3;
            const bf16_t* src = Vb + (size_t)e * 512 + j0 +
                                (slot ^ ((e >> 1) & 3)) * 8;
            __builtin_amdgcn_global_load_lds((GAS void*)src, (LAS void*)(vB + q2 * 16), 16, 0, 0);
        }
    };

    f32x4 acc2[4][4] = {};               // [m over i][n over e(wave)]
    stageV(0, 0);
    __syncthreads();
    for (int it = 0; it < 16; ++it) {
        if (it < 15) stageV((it + 1) & 1, (it + 1) * 32);
        const char* vB = smem + 8192 + (it & 1) * 32768;
        int jcb = it * 4;                // global 8-elem j-chunk base
        bf16x8 a[4], b[4];
        #pragma unroll
        for (int m = 0; m < 4; ++m) {
            int i = m * 16 + rA;
            a[m] = *(const bf16x8*)(Pl + i * 1024 + (((jcb + hb) ^ (i & 7)) << 4));
        }
        #pragma unroll
        for (int n = 0; n < 4; ++n) {
            int e = wv * 64 + n * 16 + rA;
            b[n] = *(const bf16x8*)(vB + e * 64 + ((hb ^ key) << 4));
        }
        #pragma unroll
        for (int m = 0; m < 4; ++m)
            #pragma unroll
            for (int n = 0; n < 4; ++n)
                acc2[m][n] = __builtin_amdgcn_mfma_f32_16x16x32_bf16(a[m], b[n], acc2[m][n], 0, 0, 0);
        __syncthreads();
    }

    // epilogue: D frag col = e, row = i
    #pragma unroll
    for (int m = 0; m < 4; ++m)
        #pragma unroll
        for (int n = 0; n < 4; ++n) {
            int e = wv * 64 + n * 16 + rA;
            #pragma unroll
            for (int r = 0; r < 4; ++r) {
                int i = ti + m * 16 + hb * 4 + r;
                Out[(size_t)bt * 262144 + (size_t)i * 512 + e] = acc2[m][n][r];
            }
        }
}

// ---------------------------------------------------------------------------
extern "C" void kernel_launch(void* const* d_in, const int* in_sizes, int n_in,
                              void* d_out, int out_size, void* d_ws, size_t ws_size,
                              hipStream_t stream)
{
    const float* x  = (const float*)d_in[0];
    const float* Wk = (const float*)d_in[1];
    const float* bk = (const float*)d_in[2];
    const float* Wq = (const float*)d_in[3];
    const float* bq = (const float*)d_in[4];
    const float* Wv = (const float*)d_in[5];
    const float* bv = (const float*)d_in[6];
    float* out = (float*)d_out;
    char*  ws  = (char*)d_ws;

    bf16_t* k    = (bf16_t*)(ws + 0);          // 33.55 MB
    bf16_t* q    = (bf16_t*)(ws + 33554432);   // 33.55 MB
    bf16_t* vt   = (bf16_t*)(ws + 67108864);   // 33.55 MB  v^T: [bt][e][j]
    bf16_t* xpe  = (bf16_t*)(ws + 100663296);  // 33.55 MB
    bf16_t* wkb  = (bf16_t*)(ws + 134217728);
    bf16_t* wqb  = (bf16_t*)(ws + 138412032);
    bf16_t* wvb  = (bf16_t*)(ws + 142606336);

    const long S2 = 262144;  // 512*512 per-(b,t)/per-t stride

    prep_kernel<<<3072, 256, 0, stream>>>(x, xpe, Wk, Wq, Wv, wkb, wqb, wvb);

    dim3 gg(16, 64);
    gemm_nt<1, 1><<<gg, 256, 0, stream>>>(xpe, wkb, k, bk, S2, S2, S2, 0, 1, 1.0f);
    gemm_nt<1, 1><<<gg, 256, 0, stream>>>(xpe, wqb, q, bq, S2, S2, S2, 0, 1, 1.0f);
    gemm_nt<2, 1><<<gg, 256, 0, stream>>>(wvb, xpe, vt, bv, S2, S2, S2, 1, 0, 1.0f);
    attn_fused<<<512, 512, 0, stream>>>(k, q, vt, out);
}